// Round 2
// baseline (300.582 us; speedup 1.0000x reference)
//
#include <hip/hip_runtime.h>
#include <hip/hip_bf16.h>
#include <cstdint>
#include <cstddef>

#define GAS __attribute__((address_space(1)))
#define LAS __attribute__((address_space(3)))

typedef __attribute__((ext_vector_type(8))) __bf16 bf16x8;
typedef __attribute__((ext_vector_type(4))) float f32x4;

constexpr int kB = 8, kS = 2048, kK = 1024, kH = 1024;
constexpr int kM = kB * kS;      // 16384 rows
constexpr int kN2 = 2 * kH;      // 2048 output cols of the GEMM
constexpr int kChunks = 64;
constexpr int kSc = kS / kChunks; // 32 steps per chunk

// workspace layout (bytes) -- total 115,343,360
constexpr size_t kOffXb   = 0;                    // bf16 x  (33,554,432) -- later reused as inpb
constexpr size_t kOffW0   = 33554432;             // bf16 w0 ( 4,194,304)
constexpr size_t kOffW1   = 37748736;             // bf16 w1 ( 4,194,304)
constexpr size_t kOffA    = 41943040;             // bf16 a  (33,554,432)
constexpr size_t kOffG    = 75497472;             // bf16 g  (33,554,432)
constexpr size_t kOffCA   = 109051904;            // f32 chunk A (2,097,152)
constexpr size_t kOffCV   = 111149056;            // f32 chunk V (2,097,152)
constexpr size_t kOffHst  = 113246208;            // f32 chunk h-start (2,097,152)
constexpr size_t kWsNeed  = 115343360;

__device__ __forceinline__ ushort f2bf(float f) {
    union { float f; uint32_t u; } v; v.f = f;
    uint32_t r = v.u + 0x7FFFu + ((v.u >> 16) & 1u);
    return (ushort)(r >> 16);
}
__device__ __forceinline__ float bf2f(ushort u) {
    union { uint32_t u; float f; } v; v.u = (uint32_t)u << 16;
    return v.f;
}

// ---------------- fp32 -> bf16 convert (vectorized) ----------------
__global__ void cvt_bf16_kernel(const float* __restrict__ src, ushort* __restrict__ dst, int n4) {
    int i = blockIdx.x * blockDim.x + threadIdx.x;
    if (i >= n4) return;
    f32x4 v = *reinterpret_cast<const f32x4*>(src + (size_t)i * 4);
    ushort4 o;
    o.x = f2bf(v.x); o.y = f2bf(v.y); o.z = f2bf(v.z); o.w = f2bf(v.w);
    *reinterpret_cast<ushort4*>(dst + (size_t)i * 4) = o;
}

// ---------------- GEMM: C = A(M x K, bf16) * W^T(N2 x K, bf16) + bias, fused gating epilogue
// gate cols (n < 1024):  abuf[m][n]      = sigmoid(-gate)      (bf16)
// hidden cols (n>=1024): gbuf[m][n-1024] = g(hidden)           (bf16)
__global__ __launch_bounds__(256, 2)
void gemm_epi_kernel(const ushort* __restrict__ A, const ushort* __restrict__ W,
                     const float* __restrict__ bias,
                     ushort* __restrict__ abuf, ushort* __restrict__ gbuf)
{
    __shared__ ushort As[128 * 64];
    __shared__ ushort Bs[128 * 64];

    const int tid  = threadIdx.x;
    const int lane = tid & 63;
    const int wv   = tid >> 6;
    const int bid  = blockIdx.x;
    const int tn   = bid & 15;   // 16 col tiles
    const int tm   = bid >> 4;   // 128 row tiles
    const int m0   = tm * 128;
    const int n0   = tn * 128;
    const int wm   = wv & 1, wn = wv >> 1;   // 2x2 wave grid, each wave 64x64

    f32x4 acc[4][4];
#pragma unroll
    for (int i = 0; i < 4; ++i)
#pragma unroll
        for (int j = 0; j < 4; ++j) acc[i][j] = (f32x4){0.f, 0.f, 0.f, 0.f};

    const int srow = tid >> 3;          // 0..31
    const int scol = (tid & 7) * 8;     // 0..56
    const size_t a_base = (size_t)(m0 + srow) * kK + scol;
    const size_t b_base = (size_t)(n0 + srow) * kK + scol;

    for (int kt = 0; kt < kK / 64; ++kt) {
        const int k0 = kt * 64;
#pragma unroll
        for (int i = 0; i < 4; ++i) {
            const ushort* gp = A + a_base + (size_t)i * 32 * kK + k0;
            __builtin_amdgcn_global_load_lds((const GAS void*)gp,
                (LAS void*)((char*)As + i * 4096 + wv * 1024), 16, 0, 0);
        }
#pragma unroll
        for (int i = 0; i < 4; ++i) {
            const ushort* gp = W + b_base + (size_t)i * 32 * kK + k0;
            __builtin_amdgcn_global_load_lds((const GAS void*)gp,
                (LAS void*)((char*)Bs + i * 4096 + wv * 1024), 16, 0, 0);
        }
        __syncthreads();   // compiler drains vmcnt before s_barrier
#pragma unroll
        for (int ks = 0; ks < 2; ++ks) {
            bf16x8 af[4], bfr[4];
#pragma unroll
            for (int mr = 0; mr < 4; ++mr) {
                int off = (wm * 64 + mr * 16 + (lane & 15)) * 64 + ks * 32 + (lane >> 4) * 8;
                af[mr] = *reinterpret_cast<const bf16x8*>(&As[off]);
            }
#pragma unroll
            for (int nr = 0; nr < 4; ++nr) {
                int off = (wn * 64 + nr * 16 + (lane & 15)) * 64 + ks * 32 + (lane >> 4) * 8;
                bfr[nr] = *reinterpret_cast<const bf16x8*>(&Bs[off]);
            }
#pragma unroll
            for (int mr = 0; mr < 4; ++mr)
#pragma unroll
                for (int nr = 0; nr < 4; ++nr)
                    acc[mr][nr] = __builtin_amdgcn_mfma_f32_16x16x32_bf16(af[mr], bfr[nr], acc[mr][nr], 0, 0, 0);
        }
        __syncthreads();
    }

    // Epilogue: bias + gating transform, write bf16
    const bool isGate = (tn < 8);
    ushort* outp = isGate ? abuf : gbuf;
    const int nb_local = (isGate ? tn : tn - 8) * 128 + wn * 64;
    float bn[4];
#pragma unroll
    for (int nr = 0; nr < 4; ++nr) bn[nr] = bias[n0 + wn * 64 + nr * 16 + (lane & 15)];
#pragma unroll
    for (int mr = 0; mr < 4; ++mr) {
#pragma unroll
        for (int i = 0; i < 4; ++i) {
            const int m = m0 + wm * 64 + mr * 16 + (lane >> 4) * 4 + i;
            ushort* rowp = outp + (size_t)m * kH + nb_local;
#pragma unroll
            for (int nr = 0; nr < 4; ++nr) {
                float val = acc[mr][nr][i] + bn[nr];
                float r;
                if (isGate) r = 1.f / (1.f + __expf(val));                 // sigmoid(-gate)
                else        r = (val >= 0.f) ? val + 0.5f : 1.f / (1.f + __expf(-val)); // g(hidden)
                rowp[nr * 16 + (lane & 15)] = f2bf(r);
            }
        }
    }
}

// ---------------- scan pass 1: per-chunk (A = prod a, V = combined value) ----------------
__global__ void scan_reduce_kernel(const ushort* __restrict__ abuf, const ushort* __restrict__ gbuf,
                                   float* __restrict__ cA, float* __restrict__ cV)
{
    int idx = blockIdx.x * 256 + threadIdx.x;     // 8*64*256 = 131072 threads
    int chg = idx & 255;
    int c   = (idx >> 8) & (kChunks - 1);
    int b   = idx >> 14;
    size_t ch = (size_t)chg * 4;
    size_t row = (size_t)b * kS + (size_t)c * kSc;
    const ushort* ap = abuf + row * kH + ch;
    const ushort* gp = gbuf + row * kH + ch;
    f32x4 A = (f32x4){1.f, 1.f, 1.f, 1.f};
    f32x4 V = (f32x4){0.f, 0.f, 0.f, 0.f};
    for (int t = 0; t < kSc; ++t) {
        ushort4 au = *reinterpret_cast<const ushort4*>(ap);
        ushort4 gu = *reinterpret_cast<const ushort4*>(gp);
        f32x4 a = (f32x4){bf2f(au.x), bf2f(au.y), bf2f(au.z), bf2f(au.w)};
        f32x4 g = (f32x4){bf2f(gu.x), bf2f(gu.y), bf2f(gu.z), bf2f(gu.w)};
        V = a * V + (1.f - a) * g;
        A = A * a;
        ap += kH; gp += kH;
    }
    size_t o = ((size_t)(b * kChunks + c) * kH) + ch;
    *reinterpret_cast<f32x4*>(cA + o) = A;
    *reinterpret_cast<f32x4*>(cV + o) = V;
}

// ---------------- scan pass 2: sequential scan over chunk summaries; emits h_final ----------------
__global__ void scan_chunks_kernel(const float* __restrict__ cA, const float* __restrict__ cV,
                                   const float* __restrict__ h0, float* __restrict__ hstart,
                                   float* __restrict__ hfin)
{
    int idx = blockIdx.x * 256 + threadIdx.x;     // 8*256 = 2048 threads
    int chg = idx & 255;
    int b   = idx >> 8;
    size_t ch = (size_t)chg * 4;
    f32x4 h = *reinterpret_cast<const f32x4*>(h0 + (size_t)b * kH + ch);
    for (int c = 0; c < kChunks; ++c) {
        size_t o = ((size_t)(b * kChunks + c) * kH) + ch;
        *reinterpret_cast<f32x4*>(hstart + o) = h;
        f32x4 A = *reinterpret_cast<const f32x4*>(cA + o);
        f32x4 V = *reinterpret_cast<const f32x4*>(cV + o);
        h = A * h + V;
    }
    *reinterpret_cast<f32x4*>(hfin + (size_t)b * kH + ch) = h;
}

// ---------------- scan pass 3: apply within chunk + fused residual ----------------
// L1=false: residual = x (fp32), writes inp as bf16 (for layer-1 GEMM + final residual)
// L1=true:  residual = inpb (bf16), writes final out (fp32)
template<bool L1>
__global__ void scan_apply_kernel(const ushort* __restrict__ abuf, const ushort* __restrict__ gbuf,
                                  const float* __restrict__ hstart, const void* __restrict__ addin,
                                  void* __restrict__ outp)
{
    int idx = blockIdx.x * 256 + threadIdx.x;
    int chg = idx & 255;
    int c   = (idx >> 8) & (kChunks - 1);
    int b   = idx >> 14;
    size_t ch = (size_t)chg * 4;
    size_t row = (size_t)b * kS + (size_t)c * kSc;
    size_t base = row * kH + ch;
    f32x4 h = *reinterpret_cast<const f32x4*>(hstart + ((size_t)(b * kChunks + c) * kH) + ch);
    const ushort* ap = abuf + base;
    const ushort* gp = gbuf + base;
    for (int t = 0; t < kSc; ++t) {
        ushort4 au = *reinterpret_cast<const ushort4*>(ap);
        ushort4 gu = *reinterpret_cast<const ushort4*>(gp);
        f32x4 a = (f32x4){bf2f(au.x), bf2f(au.y), bf2f(au.z), bf2f(au.w)};
        f32x4 g = (f32x4){bf2f(gu.x), bf2f(gu.y), bf2f(gu.z), bf2f(gu.w)};
        h = a * h + (1.f - a) * g;
        f32x4 r;
        if (L1) {
            ushort4 xu = *reinterpret_cast<const ushort4*>((const ushort*)addin + base + (size_t)t * kH);
            r = (f32x4){bf2f(xu.x), bf2f(xu.y), bf2f(xu.z), bf2f(xu.w)};
        } else {
            r = *reinterpret_cast<const f32x4*>((const float*)addin + base + (size_t)t * kH);
        }
        f32x4 o = h + r;
        if (L1) {
            *reinterpret_cast<f32x4*>((float*)outp + base + (size_t)t * kH) = o;
        } else {
            ushort4 ob;
            ob.x = f2bf(o.x); ob.y = f2bf(o.y); ob.z = f2bf(o.z); ob.w = f2bf(o.w);
            *reinterpret_cast<ushort4*>((ushort*)outp + base + (size_t)t * kH) = ob;
        }
        ap += kH; gp += kH;
    }
}

extern "C" void kernel_launch(void* const* d_in, const int* in_sizes, int n_in,
                              void* d_out, int out_size, void* d_ws, size_t ws_size,
                              hipStream_t stream)
{
    const float* x  = (const float*)d_in[0];
    const float* h  = (const float*)d_in[1];   // (2, 8, 1, 1024)
    const float* w0 = (const float*)d_in[2];
    const float* b0 = (const float*)d_in[3];
    const float* w1 = (const float*)d_in[4];
    const float* b1 = (const float*)d_in[5];
    float* out = (float*)d_out;
    char* ws = (char*)d_ws;

    if (ws_size < kWsNeed) return;   // diagnostic guard: wrong answer instead of page fault

    ushort* xb   = (ushort*)(ws + kOffXb);   // aliases inpb (xb dead after L0 GEMM)
    ushort* inpb = (ushort*)(ws + kOffXb);
    ushort* w0b  = (ushort*)(ws + kOffW0);
    ushort* w1b  = (ushort*)(ws + kOffW1);
    ushort* abuf = (ushort*)(ws + kOffA);
    ushort* gbuf = (ushort*)(ws + kOffG);
    float*  cA   = (float*)(ws + kOffCA);
    float*  cV   = (float*)(ws + kOffCV);
    float*  hst  = (float*)(ws + kOffHst);

    float* out_h = out + (size_t)kM * kH;    // h_final region in d_out

    // input converts to bf16
    cvt_bf16_kernel<<<(kM * kK / 4 + 255) / 256, 256, 0, stream>>>(x, xb, kM * kK / 4);
    cvt_bf16_kernel<<<(kN2 * kK / 4 + 255) / 256, 256, 0, stream>>>(w0, w0b, kN2 * kK / 4);
    cvt_bf16_kernel<<<(kN2 * kK / 4 + 255) / 256, 256, 0, stream>>>(w1, w1b, kN2 * kK / 4);

    // ---- layer 0 ----
    gemm_epi_kernel<<<(kM / 128) * (kN2 / 128), 256, 0, stream>>>(xb, w0b, b0, abuf, gbuf);
    scan_reduce_kernel<<<512, 256, 0, stream>>>(abuf, gbuf, cA, cV);
    scan_chunks_kernel<<<8, 256, 0, stream>>>(cA, cV, h, hst, out_h);
    scan_apply_kernel<false><<<512, 256, 0, stream>>>(abuf, gbuf, hst, x, inpb);

    // ---- layer 1 ----
    gemm_epi_kernel<<<(kM / 128) * (kN2 / 128), 256, 0, stream>>>(inpb, w1b, b1, abuf, gbuf);
    scan_reduce_kernel<<<512, 256, 0, stream>>>(abuf, gbuf, cA, cV);
    scan_chunks_kernel<<<8, 256, 0, stream>>>(cA, cV, h + (size_t)kB * kH, hst, out_h + (size_t)kB * kH);
    scan_apply_kernel<true><<<512, 256, 0, stream>>>(abuf, gbuf, hst, inpb, out);
}

// Round 3
// 299.605 us; speedup vs baseline: 1.0033x; 1.0033x over previous
//
#include <hip/hip_runtime.h>
#include <hip/hip_bf16.h>
#include <cstdint>
#include <cstddef>

#define GAS __attribute__((address_space(1)))
#define LAS __attribute__((address_space(3)))

typedef __attribute__((ext_vector_type(8))) __bf16 bf16x8;
typedef __attribute__((ext_vector_type(4))) float f32x4;

constexpr int kB = 8, kS = 2048, kK = 1024, kH = 1024;
constexpr int kM = kB * kS;      // 16384 rows
constexpr int kN2 = 2 * kH;      // 2048 output cols of the GEMM
constexpr int kChunks = 64;
constexpr int kSc = kS / kChunks; // 32 steps per chunk

constexpr int BM = 256, BN = 256, BK = 32;
constexpr int NKT = kK / BK;     // 32 K-tiles

// workspace layout (bytes) -- total 115,343,360
constexpr size_t kOffXb   = 0;                    // bf16 x  (33,554,432) -- later reused as inpb
constexpr size_t kOffW0   = 33554432;             // bf16 w0 ( 4,194,304)
constexpr size_t kOffW1   = 37748736;             // bf16 w1 ( 4,194,304)
constexpr size_t kOffA    = 41943040;             // bf16 a  (33,554,432)
constexpr size_t kOffG    = 75497472;             // bf16 g  (33,554,432)
constexpr size_t kOffCA   = 109051904;            // f32 chunk A (2,097,152)
constexpr size_t kOffCV   = 111149056;            // f32 chunk V (2,097,152)
constexpr size_t kOffHst  = 113246208;            // f32 chunk h-start (2,097,152)
constexpr size_t kWsNeed  = 115343360;

__device__ __forceinline__ ushort f2bf(float f) {
    union { float f; uint32_t u; } v; v.f = f;
    uint32_t r = v.u + 0x7FFFu + ((v.u >> 16) & 1u);
    return (ushort)(r >> 16);
}
__device__ __forceinline__ float bf2f(ushort u) {
    union { uint32_t u; float f; } v; v.u = (uint32_t)u << 16;
    return v.f;
}

// ---------------- fp32 -> bf16 convert (vectorized) ----------------
__global__ void cvt_bf16_kernel(const float* __restrict__ src, ushort* __restrict__ dst, int n4) {
    int i = blockIdx.x * blockDim.x + threadIdx.x;
    if (i >= n4) return;
    f32x4 v = *reinterpret_cast<const f32x4*>(src + (size_t)i * 4);
    ushort4 o;
    o.x = f2bf(v.x); o.y = f2bf(v.y); o.z = f2bf(v.z); o.w = f2bf(v.w);
    *reinterpret_cast<ushort4*>(dst + (size_t)i * 4) = o;
}

// ---------------- GEMM: C = A(16384x1024 bf16) * W^T(2048x1024 bf16) + bias, gating epilogue
// 256x256 tile, BK=32, 8 waves (2x4), 4-deep LDS ring, counted vmcnt(4), 1 barrier/K-tile.
// gate cols (n < 1024):  abuf = sigmoid(-gate); hidden cols: gbuf = g(hidden)   (bf16)
__global__ __launch_bounds__(512, 2)
void gemm_epi_kernel(const ushort* __restrict__ A, const ushort* __restrict__ W,
                     const float* __restrict__ bias,
                     ushort* __restrict__ abuf, ushort* __restrict__ gbuf)
{
    // 4 bufs x { A: 256x32, B: 256x32 } bf16 = 4 x 32KB = 128 KB
    __shared__ ushort smem[65536];

    const int tid  = threadIdx.x;
    const int lane = tid & 63;
    const int wv   = tid >> 6;     // 0..7
    const int wm   = wv >> 2;      // 0..1 : row half
    const int wn   = wv & 3;       // 0..3 : col quarter

    // XCD-bijective swizzle: 512 blocks, 8 XCDs -> each XCD: 8 tm x all 8 tn (B panel = 4MB = L2)
    const int bid = blockIdx.x;
    const int sid = (bid & 7) * 64 + (bid >> 3);
    const int tm  = sid >> 3;      // 0..63
    const int tn  = sid & 7;       // 0..7
    const int m0  = tm * BM;
    const int n0  = tn * BN;

    f32x4 acc[8][4];
#pragma unroll
    for (int i = 0; i < 8; ++i)
#pragma unroll
        for (int j = 0; j < 4; ++j) acc[i][j] = (f32x4){0.f, 0.f, 0.f, 0.f};

    // staging geometry: issue i covers rows [i*128,+128); wave wv rows [i*128+wv*16,+16)
    const int srow = wv * 16 + (lane >> 2);        // row within 128-row half
    const int scol = (lane & 3) * 8;               // 8-elem k group

#define STAGE(t_) do {                                                          \
    const int buf_ = (t_) & 3;                                                  \
    const int k0_  = (t_) * BK;                                                 \
    ushort* la_ = smem + buf_ * 16384;                                          \
    ushort* lb_ = la_ + 8192;                                                   \
    _Pragma("unroll")                                                           \
    for (int i_ = 0; i_ < 2; ++i_) {                                            \
        const ushort* ga_ = A + (size_t)(m0 + i_ * 128 + srow) * kK + k0_ + scol; \
        __builtin_amdgcn_global_load_lds((const GAS void*)ga_,                  \
            (LAS void*)((char*)(la_ + i_ * 4096 + wv * 512)), 16, 0, 0);        \
        const ushort* gb_ = W + (size_t)(n0 + i_ * 128 + srow) * kK + k0_ + scol; \
        __builtin_amdgcn_global_load_lds((const GAS void*)gb_,                  \
            (LAS void*)((char*)(lb_ + i_ * 4096 + wv * 512)), 16, 0, 0);        \
    } } while (0)

#define COMPUTE(t_) do {                                                        \
    const int buf_ = (t_) & 3;                                                  \
    const ushort* la_ = smem + buf_ * 16384 + wm * 128 * 32                     \
                        + (lane & 15) * 32 + (lane >> 4) * 8;                   \
    const ushort* lb_ = smem + buf_ * 16384 + 8192 + wn * 64 * 32               \
                        + (lane & 15) * 32 + (lane >> 4) * 8;                   \
    bf16x8 af_[8], bf_[4];                                                      \
    _Pragma("unroll")                                                           \
    for (int mf_ = 0; mf_ < 8; ++mf_)                                           \
        af_[mf_] = *reinterpret_cast<const bf16x8*>(la_ + mf_ * 512);           \
    _Pragma("unroll")                                                           \
    for (int nf_ = 0; nf_ < 4; ++nf_)                                           \
        bf_[nf_] = *reinterpret_cast<const bf16x8*>(lb_ + nf_ * 512);           \
    __builtin_amdgcn_s_setprio(1);                                              \
    _Pragma("unroll")                                                           \
    for (int mf_ = 0; mf_ < 8; ++mf_)                                           \
        _Pragma("unroll")                                                       \
        for (int nf_ = 0; nf_ < 4; ++nf_)                                       \
            acc[mf_][nf_] = __builtin_amdgcn_mfma_f32_16x16x32_bf16(            \
                af_[mf_], bf_[nf_], acc[mf_][nf_], 0, 0, 0);                    \
    __builtin_amdgcn_s_setprio(0);                                              \
    } while (0)

    STAGE(0);
    STAGE(1);
    for (int t = 0; t < NKT - 2; ++t) {
        asm volatile("s_waitcnt vmcnt(4)" ::: "memory");
        __builtin_amdgcn_s_barrier();
        __builtin_amdgcn_sched_barrier(0);
        STAGE(t + 2);
        COMPUTE(t);
    }
    asm volatile("s_waitcnt vmcnt(4)" ::: "memory");
    __builtin_amdgcn_s_barrier();
    __builtin_amdgcn_sched_barrier(0);
    COMPUTE(NKT - 2);
    asm volatile("s_waitcnt vmcnt(0)" ::: "memory");
    __builtin_amdgcn_s_barrier();
    __builtin_amdgcn_sched_barrier(0);
    COMPUTE(NKT - 1);

#undef STAGE
#undef COMPUTE

    // Epilogue: bias + gating, write bf16. tn 0..3 -> gate, 4..7 -> hidden (BN=256 | 1024)
    const bool isGate = (tn < 4);
    ushort* outp = isGate ? abuf : gbuf;
    const int ncol0 = (isGate ? tn : tn - 4) * 256 + wn * 64;
    float bn[4];
#pragma unroll
    for (int nf = 0; nf < 4; ++nf) bn[nf] = bias[n0 + wn * 64 + nf * 16 + (lane & 15)];
#pragma unroll
    for (int mf = 0; mf < 8; ++mf) {
#pragma unroll
        for (int i = 0; i < 4; ++i) {
            const int m = m0 + wm * 128 + mf * 16 + (lane >> 4) * 4 + i;
            ushort* rowp = outp + (size_t)m * kH + ncol0;
#pragma unroll
            for (int nf = 0; nf < 4; ++nf) {
                float val = acc[mf][nf][i] + bn[nf];
                float r;
                if (isGate) r = 1.f / (1.f + __expf(val));                 // sigmoid(-gate)
                else        r = (val >= 0.f) ? val + 0.5f : 1.f / (1.f + __expf(-val)); // g(hidden)
                rowp[nf * 16 + (lane & 15)] = f2bf(r);
            }
        }
    }
}

// ---------------- scan pass 1: per-chunk (A = prod a, V = combined value) ----------------
__global__ void scan_reduce_kernel(const ushort* __restrict__ abuf, const ushort* __restrict__ gbuf,
                                   float* __restrict__ cA, float* __restrict__ cV)
{
    int idx = blockIdx.x * 256 + threadIdx.x;     // 131072 threads
    int chg = idx & 255;
    int c   = (idx >> 8) & (kChunks - 1);
    int b   = idx >> 14;
    size_t ch = (size_t)chg * 4;
    size_t row = (size_t)b * kS + (size_t)c * kSc;
    const ushort* ap = abuf + row * kH + ch;
    const ushort* gp = gbuf + row * kH + ch;
    f32x4 A = (f32x4){1.f, 1.f, 1.f, 1.f};
    f32x4 V = (f32x4){0.f, 0.f, 0.f, 0.f};
    for (int t = 0; t < kSc; ++t) {
        ushort4 au = *reinterpret_cast<const ushort4*>(ap);
        ushort4 gu = *reinterpret_cast<const ushort4*>(gp);
        f32x4 a = (f32x4){bf2f(au.x), bf2f(au.y), bf2f(au.z), bf2f(au.w)};
        f32x4 g = (f32x4){bf2f(gu.x), bf2f(gu.y), bf2f(gu.z), bf2f(gu.w)};
        V = a * V + (1.f - a) * g;
        A = A * a;
        ap += kH; gp += kH;
    }
    size_t o = ((size_t)(b * kChunks + c) * kH) + ch;
    *reinterpret_cast<f32x4*>(cA + o) = A;
    *reinterpret_cast<f32x4*>(cV + o) = V;
}

// ---------------- scan pass 2: sequential scan over chunk summaries; emits h_final ----------------
__global__ void scan_chunks_kernel(const float* __restrict__ cA, const float* __restrict__ cV,
                                   const float* __restrict__ h0, float* __restrict__ hstart,
                                   float* __restrict__ hfin)
{
    int idx = blockIdx.x * 256 + threadIdx.x;     // 2048 threads
    int chg = idx & 255;
    int b   = idx >> 8;
    size_t ch = (size_t)chg * 4;
    f32x4 h = *reinterpret_cast<const f32x4*>(h0 + (size_t)b * kH + ch);
    for (int c = 0; c < kChunks; ++c) {
        size_t o = ((size_t)(b * kChunks + c) * kH) + ch;
        *reinterpret_cast<f32x4*>(hstart + o) = h;
        f32x4 A = *reinterpret_cast<const f32x4*>(cA + o);
        f32x4 V = *reinterpret_cast<const f32x4*>(cV + o);
        h = A * h + V;
    }
    *reinterpret_cast<f32x4*>(hfin + (size_t)b * kH + ch) = h;
}

// ---------------- scan pass 3: apply within chunk + fused residual ----------------
template<bool L1>
__global__ void scan_apply_kernel(const ushort* __restrict__ abuf, const ushort* __restrict__ gbuf,
                                  const float* __restrict__ hstart, const void* __restrict__ addin,
                                  void* __restrict__ outp)
{
    int idx = blockIdx.x * 256 + threadIdx.x;
    int chg = idx & 255;
    int c   = (idx >> 8) & (kChunks - 1);
    int b   = idx >> 14;
    size_t ch = (size_t)chg * 4;
    size_t row = (size_t)b * kS + (size_t)c * kSc;
    size_t base = row * kH + ch;
    f32x4 h = *reinterpret_cast<const f32x4*>(hstart + ((size_t)(b * kChunks + c) * kH) + ch);
    const ushort* ap = abuf + base;
    const ushort* gp = gbuf + base;
    for (int t = 0; t < kSc; ++t) {
        ushort4 au = *reinterpret_cast<const ushort4*>(ap);
        ushort4 gu = *reinterpret_cast<const ushort4*>(gp);
        f32x4 a = (f32x4){bf2f(au.x), bf2f(au.y), bf2f(au.z), bf2f(au.w)};
        f32x4 g = (f32x4){bf2f(gu.x), bf2f(gu.y), bf2f(gu.z), bf2f(gu.w)};
        h = a * h + (1.f - a) * g;
        f32x4 r;
        if (L1) {
            ushort4 xu = *reinterpret_cast<const ushort4*>((const ushort*)addin + base + (size_t)t * kH);
            r = (f32x4){bf2f(xu.x), bf2f(xu.y), bf2f(xu.z), bf2f(xu.w)};
        } else {
            r = *reinterpret_cast<const f32x4*>((const float*)addin + base + (size_t)t * kH);
        }
        f32x4 o = h + r;
        if (L1) {
            *reinterpret_cast<f32x4*>((float*)outp + base + (size_t)t * kH) = o;
        } else {
            ushort4 ob;
            ob.x = f2bf(o.x); ob.y = f2bf(o.y); ob.z = f2bf(o.z); ob.w = f2bf(o.w);
            *reinterpret_cast<ushort4*>((ushort*)outp + base + (size_t)t * kH) = ob;
        }
        ap += kH; gp += kH;
    }
}

extern "C" void kernel_launch(void* const* d_in, const int* in_sizes, int n_in,
                              void* d_out, int out_size, void* d_ws, size_t ws_size,
                              hipStream_t stream)
{
    const float* x  = (const float*)d_in[0];
    const float* h  = (const float*)d_in[1];   // (2, 8, 1, 1024)
    const float* w0 = (const float*)d_in[2];
    const float* b0 = (const float*)d_in[3];
    const float* w1 = (const float*)d_in[4];
    const float* b1 = (const float*)d_in[5];
    float* out = (float*)d_out;
    char* ws = (char*)d_ws;

    if (ws_size < kWsNeed) return;

    ushort* xb   = (ushort*)(ws + kOffXb);   // aliases inpb (xb dead after L0 GEMM)
    ushort* inpb = (ushort*)(ws + kOffXb);
    ushort* w0b  = (ushort*)(ws + kOffW0);
    ushort* w1b  = (ushort*)(ws + kOffW1);
    ushort* abuf = (ushort*)(ws + kOffA);
    ushort* gbuf = (ushort*)(ws + kOffG);
    float*  cA   = (float*)(ws + kOffCA);
    float*  cV   = (float*)(ws + kOffCV);
    float*  hst  = (float*)(ws + kOffHst);

    float* out_h = out + (size_t)kM * kH;    // h_final region in d_out

    cvt_bf16_kernel<<<(kM * kK / 4 + 255) / 256, 256, 0, stream>>>(x, xb, kM * kK / 4);
    cvt_bf16_kernel<<<(kN2 * kK / 4 + 255) / 256, 256, 0, stream>>>(w0, w0b, kN2 * kK / 4);
    cvt_bf16_kernel<<<(kN2 * kK / 4 + 255) / 256, 256, 0, stream>>>(w1, w1b, kN2 * kK / 4);

    const int gemm_grid = (kM / BM) * (kN2 / BN);   // 64*8 = 512

    // ---- layer 0 ----
    gemm_epi_kernel<<<gemm_grid, 512, 0, stream>>>(xb, w0b, b0, abuf, gbuf);
    scan_reduce_kernel<<<512, 256, 0, stream>>>(abuf, gbuf, cA, cV);
    scan_chunks_kernel<<<8, 256, 0, stream>>>(cA, cV, h, hst, out_h);
    scan_apply_kernel<false><<<512, 256, 0, stream>>>(abuf, gbuf, hst, x, inpb);

    // ---- layer 1 ----
    gemm_epi_kernel<<<gemm_grid, 512, 0, stream>>>(inpb, w1b, b1, abuf, gbuf);
    scan_reduce_kernel<<<512, 256, 0, stream>>>(abuf, gbuf, cA, cV);
    scan_chunks_kernel<<<8, 256, 0, stream>>>(cA, cV, h + (size_t)kB * kH, hst, out_h + (size_t)kB * kH);
    scan_apply_kernel<true><<<512, 256, 0, stream>>>(abuf, gbuf, hst, inpb, out);
}

// Round 5
// 290.116 us; speedup vs baseline: 1.0361x; 1.0327x over previous
//
#include <hip/hip_runtime.h>
#include <hip/hip_bf16.h>
#include <cstdint>
#include <cstddef>

#define GAS __attribute__((address_space(1)))
#define LAS __attribute__((address_space(3)))

typedef __attribute__((ext_vector_type(8))) __bf16 bf16x8;
typedef __attribute__((ext_vector_type(4))) float f32x4;

constexpr int kB = 8, kS = 2048, kK = 1024, kH = 1024;
constexpr int kM = kB * kS;      // 16384 rows
constexpr int kN2 = 2 * kH;      // 2048 output cols of the GEMM
constexpr int kChunks = 64;
constexpr int kSc = kS / kChunks; // 32 steps per chunk

constexpr int BM = 256, BN = 256, BK = 32;
constexpr int NKT = kK / BK;     // 32 K-tiles

// workspace layout (bytes) -- total 115,343,360
constexpr size_t kOffXb   = 0;                    // bf16 x  (33,554,432) -- later reused as inpb
constexpr size_t kOffW0   = 33554432;             // bf16 w0 ( 4,194,304)
constexpr size_t kOffW1   = 37748736;             // bf16 w1 ( 4,194,304)
constexpr size_t kOffA    = 41943040;             // bf16 a  (33,554,432)
constexpr size_t kOffG    = 75497472;             // bf16 g  (33,554,432)
constexpr size_t kOffCA   = 109051904;            // f32 chunk A (2,097,152)
constexpr size_t kOffCV   = 111149056;            // f32 chunk V (2,097,152)
constexpr size_t kOffHst  = 113246208;            // f32 chunk h-start (2,097,152)
constexpr size_t kWsNeed  = 115343360;

__device__ __forceinline__ ushort f2bf(float f) {
    union { float f; uint32_t u; } v; v.f = f;
    uint32_t r = v.u + 0x7FFFu + ((v.u >> 16) & 1u);
    return (ushort)(r >> 16);
}
__device__ __forceinline__ float bf2f(ushort u) {
    union { uint32_t u; float f; } v; v.u = (uint32_t)u << 16;
    return v.f;
}

// ---------------- fp32 -> bf16 convert (vectorized) ----------------
__global__ void cvt_bf16_kernel(const float* __restrict__ src, ushort* __restrict__ dst, int n4) {
    int i = blockIdx.x * blockDim.x + threadIdx.x;
    if (i >= n4) return;
    f32x4 v = *reinterpret_cast<const f32x4*>(src + (size_t)i * 4);
    ushort4 o;
    o.x = f2bf(v.x); o.y = f2bf(v.y); o.z = f2bf(v.z); o.w = f2bf(v.w);
    *reinterpret_cast<ushort4*>(dst + (size_t)i * 4) = o;
}

// ---------------- GEMM: C = A(16384x1024 bf16) * W^T(2048x1024 bf16) + bias, gating epilogue
// 256x256 tile, BK=32, 8 waves (2x4), 4-deep LDS ring, counted vmcnt(4), 1 barrier/K-tile.
// Ring index is COMPILE-TIME (x4 unroll); global k-advance via pointer bumps (offset arg of
// global_load_lds must stay 0: the imm offset applies to BOTH global and LDS addresses --
// round-4 NaN root cause). ds_reads ordered bf[0..3] then af[0..7] so the FIFO lgkmcnt lets
// MFMA group 0 start after 5 reads instead of 12 (round-3 pipes were serialized).
__global__ __launch_bounds__(512, 1)
void gemm_epi_kernel(const ushort* __restrict__ A, const ushort* __restrict__ W,
                     const float* __restrict__ bias,
                     ushort* __restrict__ abuf, ushort* __restrict__ gbuf)
{
    // 4 bufs x { A: 256x32 (16KB), B: 256x32 (16KB) } = 128 KB
    __shared__ ushort smem[65536];

    const int tid  = threadIdx.x;
    const int lane = tid & 63;
    const int wv   = tid >> 6;     // 0..7
    const int wm   = wv >> 2;      // 0..1 : row half
    const int wn   = wv & 3;       // 0..3 : col quarter

    // XCD-bijective swizzle: 512 blocks, 8 XCDs
    const int bid = blockIdx.x;
    const int sid = (bid & 7) * 64 + (bid >> 3);
    const int tm  = sid >> 3;      // 0..63
    const int tn  = sid & 7;       // 0..7
    const int m0  = tm * BM;
    const int n0  = tn * BN;

    f32x4 acc[8][4];
#pragma unroll
    for (int i = 0; i < 8; ++i)
#pragma unroll
        for (int j = 0; j < 4; ++j) acc[i][j] = (f32x4){0.f, 0.f, 0.f, 0.f};

    // staging geometry: lane l covers row (l>>2), 16B k-chunk (l&3); linear LDS dest = base + l*16
    const int srow = wv * 16 + (lane >> 2);
    const int scol = (lane & 3) * 8;               // elems

    const ushort* ga0 = A + (size_t)(m0 + srow) * kK + scol;          // rows   0..127
    const ushort* ga1 = ga0 + (size_t)128 * kK;                       // rows 128..255
    const ushort* gb0 = W + (size_t)(n0 + srow) * kK + scol;
    const ushort* gb1 = gb0 + (size_t)128 * kK;

    char* lds = (char*)smem;
    const int ldsw = wv * 1024;

    // per-lane LDS read offsets (bytes); bufs at +BUF*32768, B at +16384
    const int rb   = (lane & 15) * 64 + (lane >> 4) * 16;
    const int aoff = wm * 8192 + rb;
    const int boff = 16384 + wn * 4096 + rb;

#define STAGE(BUF) do {                                                          \
    __builtin_amdgcn_global_load_lds((const GAS void*)(ga0),                     \
        (LAS void*)(lds + (BUF) * 32768 + ldsw),          16, 0, 0);             \
    __builtin_amdgcn_global_load_lds((const GAS void*)(ga1),                     \
        (LAS void*)(lds + (BUF) * 32768 + 8192  + ldsw),  16, 0, 0);             \
    __builtin_amdgcn_global_load_lds((const GAS void*)(gb0),                     \
        (LAS void*)(lds + (BUF) * 32768 + 16384 + ldsw),  16, 0, 0);             \
    __builtin_amdgcn_global_load_lds((const GAS void*)(gb1),                     \
        (LAS void*)(lds + (BUF) * 32768 + 24576 + ldsw),  16, 0, 0);             \
    ga0 += BK; ga1 += BK; gb0 += BK; gb1 += BK;                                  \
  } while (0)

#define COMPUTE(BUF) do {                                                        \
    const char* lb_ = lds + (BUF) * 32768;                                       \
    bf16x8 bf_[4], af_[8];                                                       \
    _Pragma("unroll")                                                            \
    for (int nf_ = 0; nf_ < 4; ++nf_)                                            \
        bf_[nf_] = *reinterpret_cast<const bf16x8*>(lb_ + boff + nf_ * 1024);    \
    _Pragma("unroll")                                                            \
    for (int mf_ = 0; mf_ < 8; ++mf_)                                            \
        af_[mf_] = *reinterpret_cast<const bf16x8*>(lb_ + aoff + mf_ * 1024);    \
    __builtin_amdgcn_s_setprio(1);                                               \
    _Pragma("unroll")                                                            \
    for (int mf_ = 0; mf_ < 8; ++mf_)                                            \
        _Pragma("unroll")                                                        \
        for (int nf_ = 0; nf_ < 4; ++nf_)                                        \
            acc[mf_][nf_] = __builtin_amdgcn_mfma_f32_16x16x32_bf16(             \
                af_[mf_], bf_[nf_], acc[mf_][nf_], 0, 0, 0);                     \
    __builtin_amdgcn_s_setprio(0);                                               \
  } while (0)

#define TILE(BUF, STBUF) do {                                                    \
    asm volatile("s_waitcnt vmcnt(4)" ::: "memory");                             \
    __builtin_amdgcn_s_barrier();                                                \
    __builtin_amdgcn_sched_barrier(0);                                           \
    STAGE(STBUF);                                                                \
    COMPUTE(BUF);                                                                \
  } while (0)

    // prologue: stage tiles 0,1
    STAGE(0);
    STAGE(1);

    for (int g = 0; g < 7; ++g) {
        TILE(0, 2);     // compute 4g+0, stage 4g+2
        TILE(1, 3);     // compute 4g+1, stage 4g+3
        TILE(2, 0);     // compute 4g+2, stage 4g+4
        TILE(3, 1);     // compute 4g+3, stage 4g+5
    }
    // tail: computes 28..31; stages 30,31
    TILE(0, 2);
    TILE(1, 3);
    asm volatile("s_waitcnt vmcnt(4)" ::: "memory");
    __builtin_amdgcn_s_barrier();
    __builtin_amdgcn_sched_barrier(0);
    COMPUTE(2);         // tile 30
    asm volatile("s_waitcnt vmcnt(0)" ::: "memory");
    __builtin_amdgcn_s_barrier();
    __builtin_amdgcn_sched_barrier(0);
    COMPUTE(3);         // tile 31

#undef STAGE
#undef COMPUTE
#undef TILE

    // Epilogue: bias + gating, write bf16. tn 0..3 -> gate, 4..7 -> hidden
    const bool isGate = (tn < 4);
    ushort* outp = isGate ? abuf : gbuf;
    const int ncol0 = (isGate ? tn : tn - 4) * 256 + wn * 64;
    float bn[4];
#pragma unroll
    for (int nf = 0; nf < 4; ++nf) bn[nf] = bias[n0 + wn * 64 + nf * 16 + (lane & 15)];
#pragma unroll
    for (int mf = 0; mf < 8; ++mf) {
#pragma unroll
        for (int i = 0; i < 4; ++i) {
            const int m = m0 + wm * 128 + mf * 16 + (lane >> 4) * 4 + i;
            ushort* rowp = outp + (size_t)m * kH + ncol0;
#pragma unroll
            for (int nf = 0; nf < 4; ++nf) {
                float val = acc[mf][nf][i] + bn[nf];
                float r;
                if (isGate) r = 1.f / (1.f + __expf(val));                 // sigmoid(-gate)
                else        r = (val >= 0.f) ? val + 0.5f : 1.f / (1.f + __expf(-val)); // g(hidden)
                rowp[nf * 16 + (lane & 15)] = f2bf(r);
            }
        }
    }
}

// ---------------- scan pass 1: per-chunk (A = prod a, V = combined value) ----------------
__global__ void scan_reduce_kernel(const ushort* __restrict__ abuf, const ushort* __restrict__ gbuf,
                                   float* __restrict__ cA, float* __restrict__ cV)
{
    int idx = blockIdx.x * 256 + threadIdx.x;     // 131072 threads
    int chg = idx & 255;
    int c   = (idx >> 8) & (kChunks - 1);
    int b   = idx >> 14;
    size_t ch = (size_t)chg * 4;
    size_t row = (size_t)b * kS + (size_t)c * kSc;
    const ushort* ap = abuf + row * kH + ch;
    const ushort* gp = gbuf + row * kH + ch;
    f32x4 A = (f32x4){1.f, 1.f, 1.f, 1.f};
    f32x4 V = (f32x4){0.f, 0.f, 0.f, 0.f};
    for (int t = 0; t < kSc; ++t) {
        ushort4 au = *reinterpret_cast<const ushort4*>(ap);
        ushort4 gu = *reinterpret_cast<const ushort4*>(gp);
        f32x4 a = (f32x4){bf2f(au.x), bf2f(au.y), bf2f(au.z), bf2f(au.w)};
        f32x4 g = (f32x4){bf2f(gu.x), bf2f(gu.y), bf2f(gu.z), bf2f(gu.w)};
        V = a * V + (1.f - a) * g;
        A = A * a;
        ap += kH; gp += kH;
    }
    size_t o = ((size_t)(b * kChunks + c) * kH) + ch;
    *reinterpret_cast<f32x4*>(cA + o) = A;
    *reinterpret_cast<f32x4*>(cV + o) = V;
}

// ---------------- scan pass 2: sequential scan over chunk summaries; emits h_final ----------------
__global__ void scan_chunks_kernel(const float* __restrict__ cA, const float* __restrict__ cV,
                                   const float* __restrict__ h0, float* __restrict__ hstart,
                                   float* __restrict__ hfin)
{
    int idx = blockIdx.x * 256 + threadIdx.x;     // 2048 threads
    int chg = idx & 255;
    int b   = idx >> 8;
    size_t ch = (size_t)chg * 4;
    f32x4 h = *reinterpret_cast<const f32x4*>(h0 + (size_t)b * kH + ch);
    for (int c = 0; c < kChunks; ++c) {
        size_t o = ((size_t)(b * kChunks + c) * kH) + ch;
        *reinterpret_cast<f32x4*>(hstart + o) = h;
        f32x4 A = *reinterpret_cast<const f32x4*>(cA + o);
        f32x4 V = *reinterpret_cast<const f32x4*>(cV + o);
        h = A * h + V;
    }
    *reinterpret_cast<f32x4*>(hfin + (size_t)b * kH + ch) = h;
}

// ---------------- scan pass 3: apply within chunk + fused residual ----------------
// Residual input is always bf16. WRITE_F32=false: write bf16 (layer-0 inp, in-place over xb).
// WRITE_F32=true: write fp32 (final out). In-place is elementwise-safe (same thread,
// read-then-write same address).
template<bool WRITE_F32>
__global__ void scan_apply_kernel(const ushort* __restrict__ abuf, const ushort* __restrict__ gbuf,
                                  const float* __restrict__ hstart, const ushort* __restrict__ addin,
                                  void* __restrict__ outp)
{
    int idx = blockIdx.x * 256 + threadIdx.x;
    int chg = idx & 255;
    int c   = (idx >> 8) & (kChunks - 1);
    int b   = idx >> 14;
    size_t ch = (size_t)chg * 4;
    size_t row = (size_t)b * kS + (size_t)c * kSc;
    size_t base = row * kH + ch;
    f32x4 h = *reinterpret_cast<const f32x4*>(hstart + ((size_t)(b * kChunks + c) * kH) + ch);
    const ushort* ap = abuf + base;
    const ushort* gp = gbuf + base;
    for (int t = 0; t < kSc; ++t) {
        ushort4 au = *reinterpret_cast<const ushort4*>(ap);
        ushort4 gu = *reinterpret_cast<const ushort4*>(gp);
        f32x4 a = (f32x4){bf2f(au.x), bf2f(au.y), bf2f(au.z), bf2f(au.w)};
        f32x4 g = (f32x4){bf2f(gu.x), bf2f(gu.y), bf2f(gu.z), bf2f(gu.w)};
        h = a * h + (1.f - a) * g;
        ushort4 xu = *reinterpret_cast<const ushort4*>(addin + base + (size_t)t * kH);
        f32x4 r = (f32x4){bf2f(xu.x), bf2f(xu.y), bf2f(xu.z), bf2f(xu.w)};
        f32x4 o = h + r;
        if (WRITE_F32) {
            *reinterpret_cast<f32x4*>((float*)outp + base + (size_t)t * kH) = o;
        } else {
            ushort4 ob;
            ob.x = f2bf(o.x); ob.y = f2bf(o.y); ob.z = f2bf(o.z); ob.w = f2bf(o.w);
            *reinterpret_cast<ushort4*>((ushort*)outp + base + (size_t)t * kH) = ob;
        }
        ap += kH; gp += kH;
    }
}

extern "C" void kernel_launch(void* const* d_in, const int* in_sizes, int n_in,
                              void* d_out, int out_size, void* d_ws, size_t ws_size,
                              hipStream_t stream)
{
    const float* x  = (const float*)d_in[0];
    const float* h  = (const float*)d_in[1];   // (2, 8, 1, 1024)
    const float* w0 = (const float*)d_in[2];
    const float* b0 = (const float*)d_in[3];
    const float* w1 = (const float*)d_in[4];
    const float* b1 = (const float*)d_in[5];
    float* out = (float*)d_out;
    char* ws = (char*)d_ws;

    if (ws_size < kWsNeed) return;

    ushort* xb   = (ushort*)(ws + kOffXb);   // aliases inpb (apply-L0 overwrites in place)
    ushort* inpb = (ushort*)(ws + kOffXb);
    ushort* w0b  = (ushort*)(ws + kOffW0);
    ushort* w1b  = (ushort*)(ws + kOffW1);
    ushort* abuf = (ushort*)(ws + kOffA);
    ushort* gbuf = (ushort*)(ws + kOffG);
    float*  cA   = (float*)(ws + kOffCA);
    float*  cV   = (float*)(ws + kOffCV);
    float*  hst  = (float*)(ws + kOffHst);

    float* out_h = out + (size_t)kM * kH;    // h_final region in d_out

    cvt_bf16_kernel<<<(kM * kK / 4 + 255) / 256, 256, 0, stream>>>(x, xb, kM * kK / 4);
    cvt_bf16_kernel<<<(kN2 * kK / 4 + 255) / 256, 256, 0, stream>>>(w0, w0b, kN2 * kK / 4);
    cvt_bf16_kernel<<<(kN2 * kK / 4 + 255) / 256, 256, 0, stream>>>(w1, w1b, kN2 * kK / 4);

    const int gemm_grid = (kM / BM) * (kN2 / BN);   // 512

    // ---- layer 0 ----
    gemm_epi_kernel<<<gemm_grid, 512, 0, stream>>>(xb, w0b, b0, abuf, gbuf);
    scan_reduce_kernel<<<512, 256, 0, stream>>>(abuf, gbuf, cA, cV);
    scan_chunks_kernel<<<8, 256, 0, stream>>>(cA, cV, h, hst, out_h);
    scan_apply_kernel<false><<<512, 256, 0, stream>>>(abuf, gbuf, hst, xb, inpb);

    // ---- layer 1 ----
    gemm_epi_kernel<<<gemm_grid, 512, 0, stream>>>(inpb, w1b, b1, abuf, gbuf);
    scan_reduce_kernel<<<512, 256, 0, stream>>>(abuf, gbuf, cA, cV);
    scan_chunks_kernel<<<8, 256, 0, stream>>>(cA, cV, h + (size_t)kB * kH, hst, out_h + (size_t)kB * kH);
    scan_apply_kernel<true><<<512, 256, 0, stream>>>(abuf, gbuf, hst, inpb, out);
}

// Round 6
// 289.391 us; speedup vs baseline: 1.0387x; 1.0025x over previous
//
#include <hip/hip_runtime.h>
#include <hip/hip_bf16.h>
#include <cstdint>
#include <cstddef>

#define GAS __attribute__((address_space(1)))
#define LAS __attribute__((address_space(3)))

typedef __attribute__((ext_vector_type(8))) __bf16 bf16x8;
typedef __attribute__((ext_vector_type(4))) float f32x4;

constexpr int kB = 8, kS = 2048, kK = 1024, kH = 1024;
constexpr int kM = kB * kS;      // 16384 rows
constexpr int kN2 = 2 * kH;      // 2048 output cols of the GEMM
constexpr int kChunks = 64;
constexpr int kSc = kS / kChunks; // 32 steps per chunk

constexpr int BM = 256, BN = 256, BK = 32;
constexpr int NKT = kK / BK;     // 32 K-tiles

// workspace layout (bytes) -- total 115,343,360
constexpr size_t kOffXb   = 0;                    // bf16 x  (33,554,432) -- later reused as inpb
constexpr size_t kOffW0   = 33554432;             // bf16 w0 ( 4,194,304)
constexpr size_t kOffW1   = 37748736;             // bf16 w1 ( 4,194,304)
constexpr size_t kOffA    = 41943040;             // bf16 a  (33,554,432)
constexpr size_t kOffG    = 75497472;             // bf16 g  (33,554,432)
constexpr size_t kOffCA   = 109051904;            // f32 chunk A (2,097,152)
constexpr size_t kOffCV   = 111149056;            // f32 chunk V (2,097,152)
constexpr size_t kOffHst  = 113246208;            // f32 chunk h-start (2,097,152)
constexpr size_t kWsNeed  = 115343360;

__device__ __forceinline__ ushort f2bf(float f) {
    union { float f; uint32_t u; } v; v.f = f;
    uint32_t r = v.u + 0x7FFFu + ((v.u >> 16) & 1u);
    return (ushort)(r >> 16);
}
__device__ __forceinline__ float bf2f(ushort u) {
    union { uint32_t u; float f; } v; v.u = (uint32_t)u << 16;
    return v.f;
}

// ---------------- fp32 -> bf16 convert (vectorized) ----------------
__global__ void cvt_bf16_kernel(const float* __restrict__ src, ushort* __restrict__ dst, int n4) {
    int i = blockIdx.x * blockDim.x + threadIdx.x;
    if (i >= n4) return;
    f32x4 v = *reinterpret_cast<const f32x4*>(src + (size_t)i * 4);
    ushort4 o;
    o.x = f2bf(v.x); o.y = f2bf(v.y); o.z = f2bf(v.z); o.w = f2bf(v.w);
    *reinterpret_cast<ushort4*>(dst + (size_t)i * 4) = o;
}

// ---------------- GEMM: C = A(16384x1024 bf16) * W^T(2048x1024 bf16) + bias, gating epilogue
// 256x256 tile, BK=32, 8 waves (2x4), 4-deep LDS ring, counted vmcnt(4).
// 8-phase-style schedule (T3+T4): each K-tile = 2 phases, each {ds_read subtile + stage-issue
// -> s_barrier -> lgkmcnt(0)+sched_barrier -> setprio(1) 16 MFMA setprio(0) -> s_barrier};
// vmcnt(4) once per tile before the tile-end barrier (never 0 in main loop).
// T2 swizzle (slot' = slot ^ ((row>>1)&3)) applied BOTH sides: pre-swizzled global source
// (linear global_load_lds dest) + swizzled ds_read slot -> 2-way banks only (free).
__global__ __launch_bounds__(512, 1)
void gemm_epi_kernel(const ushort* __restrict__ A, const ushort* __restrict__ W,
                     const float* __restrict__ bias,
                     ushort* __restrict__ abuf, ushort* __restrict__ gbuf)
{
    // 4 bufs x { A: 256x32 (16KB), B: 256x32 (16KB) } = 128 KB
    __shared__ ushort smem[65536];

    const int tid  = threadIdx.x;
    const int lane = tid & 63;
    const int wv   = tid >> 6;     // 0..7
    const int wm   = wv >> 2;      // 0..1 : row half
    const int wn   = wv & 3;       // 0..3 : col quarter

    // XCD-bijective swizzle: 512 blocks, 8 XCDs
    const int bid = blockIdx.x;
    const int sid = (bid & 7) * 64 + (bid >> 3);
    const int tm  = sid >> 3;      // 0..63
    const int tn  = sid & 7;       // 0..7
    const int m0  = tm * BM;
    const int n0  = tn * BN;

    f32x4 acc[8][4];
#pragma unroll
    for (int i = 0; i < 8; ++i)
#pragma unroll
        for (int j = 0; j < 4; ++j) acc[i][j] = (f32x4){0.f, 0.f, 0.f, 0.f};

    // staging: lane l -> row (l>>2), linear dest slot (l&3); global source k-slot is
    // pre-swizzled: sslot = (l&3) ^ ((srow>>1)&3) = (l&3) ^ ((l>>3)&3)
    const int srow  = wv * 16 + (lane >> 2);
    const int sslot = (lane & 3) ^ ((lane >> 3) & 3);
    const int scol  = sslot * 8;   // elems

    const ushort* ga0 = A + (size_t)(m0 + srow) * kK + scol;          // rows   0..127
    const ushort* ga1 = ga0 + (size_t)128 * kK;                       // rows 128..255
    const ushort* gb0 = W + (size_t)(n0 + srow) * kK + scol;
    const ushort* gb1 = gb0 + (size_t)128 * kK;

    char* lds = (char*)smem;
    const int ldsw = wv * 1024;

    // reads: row_in_half = frag*16 + (lane&15); k-slot wanted = lane>>4;
    // swizzled slot = (lane>>4) ^ ((row>>1)&3) = (lane>>4) ^ ((lane>>1)&3)
    const int rslot = (lane >> 4) ^ ((lane >> 1) & 3);
    const int rb    = (lane & 15) * 64 + rslot * 16;
    const int aoff  = wm * 8192 + rb;
    const int boff  = 16384 + wn * 4096 + rb;

#define VMWAIT(N) asm volatile("s_waitcnt vmcnt(" #N ")" ::: "memory")

#define STAGE_A(SBUF) do {                                                       \
    __builtin_amdgcn_global_load_lds((const GAS void*)(ga0),                     \
        (LAS void*)(lds + (SBUF) * 32768 + ldsw),          16, 0, 0);            \
    __builtin_amdgcn_global_load_lds((const GAS void*)(ga1),                     \
        (LAS void*)(lds + (SBUF) * 32768 + 8192  + ldsw),  16, 0, 0);            \
  } while (0)

#define STAGE_B(SBUF) do {                                                       \
    __builtin_amdgcn_global_load_lds((const GAS void*)(gb0),                     \
        (LAS void*)(lds + (SBUF) * 32768 + 16384 + ldsw),  16, 0, 0);            \
    __builtin_amdgcn_global_load_lds((const GAS void*)(gb1),                     \
        (LAS void*)(lds + (SBUF) * 32768 + 24576 + ldsw),  16, 0, 0);            \
    ga0 += BK; ga1 += BK; gb0 += BK; gb1 += BK;                                  \
  } while (0)

// One K-tile = 2 phases. SA/SB are the stage statements; EW the end-of-tile wait.
#define TILE_GEN(BUF, SA, SB, EW) do {                                           \
    bf16x8 bf_[4], af_[4];                                                       \
    _Pragma("unroll")                                                            \
    for (int nf_ = 0; nf_ < 4; ++nf_)                                            \
        bf_[nf_] = *reinterpret_cast<const bf16x8*>(                             \
            lds + (BUF) * 32768 + boff + nf_ * 1024);                            \
    _Pragma("unroll")                                                            \
    for (int mf_ = 0; mf_ < 4; ++mf_)                                            \
        af_[mf_] = *reinterpret_cast<const bf16x8*>(                             \
            lds + (BUF) * 32768 + aoff + mf_ * 1024);                            \
    SA;                                                                          \
    __builtin_amdgcn_s_barrier();                                                \
    asm volatile("s_waitcnt lgkmcnt(0)" ::: "memory");                           \
    __builtin_amdgcn_sched_barrier(0);                                           \
    __builtin_amdgcn_s_setprio(1);                                               \
    _Pragma("unroll")                                                            \
    for (int mf_ = 0; mf_ < 4; ++mf_)                                            \
        _Pragma("unroll")                                                        \
        for (int nf_ = 0; nf_ < 4; ++nf_)                                        \
            acc[mf_][nf_] = __builtin_amdgcn_mfma_f32_16x16x32_bf16(             \
                af_[mf_], bf_[nf_], acc[mf_][nf_], 0, 0, 0);                     \
    __builtin_amdgcn_s_setprio(0);                                               \
    __builtin_amdgcn_s_barrier();                                                \
    _Pragma("unroll")                                                            \
    for (int mf_ = 0; mf_ < 4; ++mf_)                                            \
        af_[mf_] = *reinterpret_cast<const bf16x8*>(                             \
            lds + (BUF) * 32768 + aoff + 4096 + mf_ * 1024);                     \
    SB;                                                                          \
    __builtin_amdgcn_s_barrier();                                                \
    asm volatile("s_waitcnt lgkmcnt(0)" ::: "memory");                           \
    __builtin_amdgcn_sched_barrier(0);                                           \
    __builtin_amdgcn_s_setprio(1);                                               \
    _Pragma("unroll")                                                            \
    for (int mf_ = 0; mf_ < 4; ++mf_)                                            \
        _Pragma("unroll")                                                        \
        for (int nf_ = 0; nf_ < 4; ++nf_)                                        \
            acc[4 + mf_][nf_] = __builtin_amdgcn_mfma_f32_16x16x32_bf16(         \
                af_[mf_], bf_[nf_], acc[4 + mf_][nf_], 0, 0, 0);                 \
    __builtin_amdgcn_s_setprio(0);                                               \
    EW;                                                                          \
    __builtin_amdgcn_s_barrier();                                                \
  } while (0)

#define TILE(BUF, SBUF) TILE_GEN(BUF, STAGE_A(SBUF), STAGE_B(SBUF), VMWAIT(4))
#define TAIL0(BUF)      TILE_GEN(BUF, (void)0, (void)0, VMWAIT(0))
#define TAIL1(BUF)      TILE_GEN(BUF, (void)0, (void)0, (void)0)

    // prologue: stage tiles 0,1; retire tile 0; publish
    STAGE_A(0); STAGE_B(0);
    STAGE_A(1); STAGE_B(1);
    VMWAIT(4);
    __builtin_amdgcn_s_barrier();

    for (int g = 0; g < 7; ++g) {
        TILE(0, 2);     // compute 4g+0, stage 4g+2
        TILE(1, 3);     // compute 4g+1, stage 4g+3
        TILE(2, 0);     // compute 4g+2, stage 4g+4
        TILE(3, 1);     // compute 4g+3, stage 4g+5
    }
    // tail: computes 28..31; stages 30,31
    TILE(0, 2);
    TILE(1, 3);
    TAIL0(2);           // tile 30; end-wait vmcnt(0) retires stage 31
    TAIL1(3);           // tile 31

#undef TILE
#undef TAIL0
#undef TAIL1
#undef TILE_GEN
#undef STAGE_A
#undef STAGE_B
#undef VMWAIT

    // Epilogue: bias + gating, write bf16. tn 0..3 -> gate, 4..7 -> hidden
    const bool isGate = (tn < 4);
    ushort* outp = isGate ? abuf : gbuf;
    const int ncol0 = (isGate ? tn : tn - 4) * 256 + wn * 64;
    float bn[4];
#pragma unroll
    for (int nf = 0; nf < 4; ++nf) bn[nf] = bias[n0 + wn * 64 + nf * 16 + (lane & 15)];
#pragma unroll
    for (int mf = 0; mf < 8; ++mf) {
#pragma unroll
        for (int i = 0; i < 4; ++i) {
            const int m = m0 + wm * 128 + mf * 16 + (lane >> 4) * 4 + i;
            ushort* rowp = outp + (size_t)m * kH + ncol0;
#pragma unroll
            for (int nf = 0; nf < 4; ++nf) {
                float val = acc[mf][nf][i] + bn[nf];
                float r;
                if (isGate) r = 1.f / (1.f + __expf(val));                 // sigmoid(-gate)
                else        r = (val >= 0.f) ? val + 0.5f : 1.f / (1.f + __expf(-val)); // g(hidden)
                rowp[nf * 16 + (lane & 15)] = f2bf(r);
            }
        }
    }
}

// ---------------- scan pass 1: per-chunk (A = prod a, V = combined value) ----------------
__global__ void scan_reduce_kernel(const ushort* __restrict__ abuf, const ushort* __restrict__ gbuf,
                                   float* __restrict__ cA, float* __restrict__ cV)
{
    int idx = blockIdx.x * 256 + threadIdx.x;     // 131072 threads
    int chg = idx & 255;
    int c   = (idx >> 8) & (kChunks - 1);
    int b   = idx >> 14;
    size_t ch = (size_t)chg * 4;
    size_t row = (size_t)b * kS + (size_t)c * kSc;
    const ushort* ap = abuf + row * kH + ch;
    const ushort* gp = gbuf + row * kH + ch;
    f32x4 A = (f32x4){1.f, 1.f, 1.f, 1.f};
    f32x4 V = (f32x4){0.f, 0.f, 0.f, 0.f};
    for (int t = 0; t < kSc; ++t) {
        ushort4 au = *reinterpret_cast<const ushort4*>(ap);
        ushort4 gu = *reinterpret_cast<const ushort4*>(gp);
        f32x4 a = (f32x4){bf2f(au.x), bf2f(au.y), bf2f(au.z), bf2f(au.w)};
        f32x4 g = (f32x4){bf2f(gu.x), bf2f(gu.y), bf2f(gu.z), bf2f(gu.w)};
        V = a * V + (1.f - a) * g;
        A = A * a;
        ap += kH; gp += kH;
    }
    size_t o = ((size_t)(b * kChunks + c) * kH) + ch;
    *reinterpret_cast<f32x4*>(cA + o) = A;
    *reinterpret_cast<f32x4*>(cV + o) = V;
}

// ---------------- scan pass 2: sequential scan over chunk summaries; emits h_final ----------------
__global__ void scan_chunks_kernel(const float* __restrict__ cA, const float* __restrict__ cV,
                                   const float* __restrict__ h0, float* __restrict__ hstart,
                                   float* __restrict__ hfin)
{
    int idx = blockIdx.x * 256 + threadIdx.x;     // 2048 threads
    int chg = idx & 255;
    int b   = idx >> 8;
    size_t ch = (size_t)chg * 4;
    f32x4 h = *reinterpret_cast<const f32x4*>(h0 + (size_t)b * kH + ch);
    for (int c = 0; c < kChunks; ++c) {
        size_t o = ((size_t)(b * kChunks + c) * kH) + ch;
        *reinterpret_cast<f32x4*>(hstart + o) = h;
        f32x4 A = *reinterpret_cast<const f32x4*>(cA + o);
        f32x4 V = *reinterpret_cast<const f32x4*>(cV + o);
        h = A * h + V;
    }
    *reinterpret_cast<f32x4*>(hfin + (size_t)b * kH + ch) = h;
}

// ---------------- scan pass 3: apply within chunk + fused residual ----------------
// Residual input is always bf16. WRITE_F32=false: write bf16 (layer-0 inp, in-place over xb).
// WRITE_F32=true: write fp32 (final out). In-place is elementwise-safe (same thread,
// read-then-write same address).
template<bool WRITE_F32>
__global__ void scan_apply_kernel(const ushort* __restrict__ abuf, const ushort* __restrict__ gbuf,
                                  const float* __restrict__ hstart, const ushort* __restrict__ addin,
                                  void* __restrict__ outp)
{
    int idx = blockIdx.x * 256 + threadIdx.x;
    int chg = idx & 255;
    int c   = (idx >> 8) & (kChunks - 1);
    int b   = idx >> 14;
    size_t ch = (size_t)chg * 4;
    size_t row = (size_t)b * kS + (size_t)c * kSc;
    size_t base = row * kH + ch;
    f32x4 h = *reinterpret_cast<const f32x4*>(hstart + ((size_t)(b * kChunks + c) * kH) + ch);
    const ushort* ap = abuf + base;
    const ushort* gp = gbuf + base;
    for (int t = 0; t < kSc; ++t) {
        ushort4 au = *reinterpret_cast<const ushort4*>(ap);
        ushort4 gu = *reinterpret_cast<const ushort4*>(gp);
        f32x4 a = (f32x4){bf2f(au.x), bf2f(au.y), bf2f(au.z), bf2f(au.w)};
        f32x4 g = (f32x4){bf2f(gu.x), bf2f(gu.y), bf2f(gu.z), bf2f(gu.w)};
        h = a * h + (1.f - a) * g;
        ushort4 xu = *reinterpret_cast<const ushort4*>(addin + base + (size_t)t * kH);
        f32x4 r = (f32x4){bf2f(xu.x), bf2f(xu.y), bf2f(xu.z), bf2f(xu.w)};
        f32x4 o = h + r;
        if (WRITE_F32) {
            *reinterpret_cast<f32x4*>((float*)outp + base + (size_t)t * kH) = o;
        } else {
            ushort4 ob;
            ob.x = f2bf(o.x); ob.y = f2bf(o.y); ob.z = f2bf(o.z); ob.w = f2bf(o.w);
            *reinterpret_cast<ushort4*>((ushort*)outp + base + (size_t)t * kH) = ob;
        }
        ap += kH; gp += kH;
    }
}

extern "C" void kernel_launch(void* const* d_in, const int* in_sizes, int n_in,
                              void* d_out, int out_size, void* d_ws, size_t ws_size,
                              hipStream_t stream)
{
    const float* x  = (const float*)d_in[0];
    const float* h  = (const float*)d_in[1];   // (2, 8, 1, 1024)
    const float* w0 = (const float*)d_in[2];
    const float* b0 = (const float*)d_in[3];
    const float* w1 = (const float*)d_in[4];
    const float* b1 = (const float*)d_in[5];
    float* out = (float*)d_out;
    char* ws = (char*)d_ws;

    if (ws_size < kWsNeed) return;

    ushort* xb   = (ushort*)(ws + kOffXb);   // aliases inpb (apply-L0 overwrites in place)
    ushort* inpb = (ushort*)(ws + kOffXb);
    ushort* w0b  = (ushort*)(ws + kOffW0);
    ushort* w1b  = (ushort*)(ws + kOffW1);
    ushort* abuf = (ushort*)(ws + kOffA);
    ushort* gbuf = (ushort*)(ws + kOffG);
    float*  cA   = (float*)(ws + kOffCA);
    float*  cV   = (float*)(ws + kOffCV);
    float*  hst  = (float*)(ws + kOffHst);

    float* out_h = out + (size_t)kM * kH;    // h_final region in d_out

    cvt_bf16_kernel<<<(kM * kK / 4 + 255) / 256, 256, 0, stream>>>(x, xb, kM * kK / 4);
    cvt_bf16_kernel<<<(kN2 * kK / 4 + 255) / 256, 256, 0, stream>>>(w0, w0b, kN2 * kK / 4);
    cvt_bf16_kernel<<<(kN2 * kK / 4 + 255) / 256, 256, 0, stream>>>(w1, w1b, kN2 * kK / 4);

    const int gemm_grid = (kM / BM) * (kN2 / BN);   // 512

    // ---- layer 0 ----
    gemm_epi_kernel<<<gemm_grid, 512, 0, stream>>>(xb, w0b, b0, abuf, gbuf);
    scan_reduce_kernel<<<512, 256, 0, stream>>>(abuf, gbuf, cA, cV);
    scan_chunks_kernel<<<8, 256, 0, stream>>>(cA, cV, h, hst, out_h);
    scan_apply_kernel<false><<<512, 256, 0, stream>>>(abuf, gbuf, hst, xb, inpb);

    // ---- layer 1 ----
    gemm_epi_kernel<<<gemm_grid, 512, 0, stream>>>(inpb, w1b, b1, abuf, gbuf);
    scan_reduce_kernel<<<512, 256, 0, stream>>>(abuf, gbuf, cA, cV);
    scan_chunks_kernel<<<8, 256, 0, stream>>>(cA, cV, h + (size_t)kB * kH, hst, out_h + (size_t)kB * kH);
    scan_apply_kernel<true><<<512, 256, 0, stream>>>(abuf, gbuf, hst, inpb, out);
}

// Round 7
// 272.059 us; speedup vs baseline: 1.1048x; 1.0637x over previous
//
#include <hip/hip_runtime.h>
#include <hip/hip_bf16.h>
#include <cstdint>
#include <cstddef>

#define GAS __attribute__((address_space(1)))
#define LAS __attribute__((address_space(3)))

typedef __attribute__((ext_vector_type(8))) __bf16 bf16x8;
typedef __attribute__((ext_vector_type(4))) float f32x4;

constexpr int kB = 8, kS = 2048, kK = 1024, kH = 1024;
constexpr int kM = kB * kS;      // 16384 rows
constexpr int kN2 = 2 * kH;      // 2048 output cols of the GEMM
constexpr int BM = 256, BN = 256, BK = 32;
constexpr int NKT = kK / BK;     // 32 K-tiles

// workspace layout (bytes)
constexpr size_t kOffXb   = 0;                    // bf16 x  (33,554,432) -- later reused as inpb
constexpr size_t kOffW0   = 33554432;             // bf16 w0 ( 4,194,304)
constexpr size_t kOffW1   = 37748736;             // bf16 w1 ( 4,194,304)
constexpr size_t kOffA    = 41943040;             // bf16 A_pref (33,554,432)
constexpr size_t kOffG    = 75497472;             // bf16 V_pref (33,554,432)
constexpr size_t kOffCA   = 109051904;            // f32 chunk A (64*1024*4 = 262,144)
constexpr size_t kOffCV   = 111149056;            // f32 chunk V (262,144)
constexpr size_t kOffHst  = 113246208;            // f32 chunk h-start (262,144)
constexpr size_t kWsNeed  = 115343360;

__device__ __forceinline__ ushort f2bf(float f) {
    union { float f; uint32_t u; } v; v.f = f;
    uint32_t r = v.u + 0x7FFFu + ((v.u >> 16) & 1u);
    return (ushort)(r >> 16);
}
__device__ __forceinline__ float bf2f(ushort u) {
    union { uint32_t u; float f; } v; v.u = (uint32_t)u << 16;
    return v.f;
}

// ---------------- fp32 -> bf16 convert (vectorized) ----------------
__global__ void cvt_bf16_kernel(const float* __restrict__ src, ushort* __restrict__ dst, int n4) {
    int i = blockIdx.x * blockDim.x + threadIdx.x;
    if (i >= n4) return;
    f32x4 v = *reinterpret_cast<const f32x4*>(src + (size_t)i * 4);
    ushort4 o;
    o.x = f2bf(v.x); o.y = f2bf(v.y); o.z = f2bf(v.z); o.w = f2bf(v.w);
    *reinterpret_cast<ushort4*>(dst + (size_t)i * 4) = o;
}

// ---------------- GEMM + gating + fused block-local scan ----------------
// Per block: 256 m-rows (one b, 256 contiguous s-steps = one chunk) x 128 j-columns,
// computing BOTH gate (W rows j0..j0+127) and hidden (W rows 1024+j0..) for those j.
// K-loop: 4-deep LDS ring, counted vmcnt(4), 2 phases/K-tile, T2 swizzle (validated r6).
// Epilogue: a=sigmoid(-gate), g(hidden) -> LDS; 128j x 4seg threads run f32 prefix scan
// over the 256 steps; store per-element A_pref/V_pref (bf16) + chunk summary (f32).
__global__ __launch_bounds__(512, 1)
void gemm_scan_kernel(const ushort* __restrict__ A, const ushort* __restrict__ W,
                      const float* __restrict__ bias,
                      ushort* __restrict__ Apref, ushort* __restrict__ Vpref,
                      float* __restrict__ cA, float* __restrict__ cV)
{
    // K-loop: 4 ring bufs x 32KB = 131072 B. Epilogue scan: a_lds/g_lds [256][132] bf16
    // (2*67584) + seg sums (4096) = 139264 B. Union: 69632 ushorts.
    __shared__ ushort smem[69632];

    const int tid  = threadIdx.x;
    const int lane = tid & 63;
    const int wv   = tid >> 6;     // 0..7
    const int wm   = wv >> 2;      // 0..1 : row half
    const int wn   = wv & 3;       // 0..3 : col quarter

    // XCD-bijective swizzle: 512 blocks, 8 XCDs
    const int bid = blockIdx.x;
    const int sid = (bid & 7) * 64 + (bid >> 3);
    const int tm  = sid >> 3;      // 0..63
    const int tn  = sid & 7;       // 0..7
    const int m0  = tm * BM;
    const int j0  = tn * 128;      // this block's 128 j-columns

    f32x4 acc[8][4];
#pragma unroll
    for (int i = 0; i < 8; ++i)
#pragma unroll
        for (int j = 0; j < 4; ++j) acc[i][j] = (f32x4){0.f, 0.f, 0.f, 0.f};

    // staging: lane l -> row (l>>2), linear dest slot (l&3); pre-swizzled global k-slot
    const int srow  = wv * 16 + (lane >> 2);
    const int sslot = (lane & 3) ^ ((lane >> 3) & 3);
    const int scol  = sslot * 8;   // elems

    const ushort* ga0 = A + (size_t)(m0 + srow) * kK + scol;            // A rows   0..127
    const ushort* ga1 = ga0 + (size_t)128 * kK;                         // A rows 128..255
    const ushort* gb0 = W + (size_t)(j0 + srow) * kK + scol;            // gate rows
    const ushort* gb1 = W + (size_t)(1024 + j0 + srow) * kK + scol;     // hidden rows

    char* lds = (char*)smem;
    const int ldsw = wv * 1024;

    const int rslot = (lane >> 4) ^ ((lane >> 1) & 3);
    const int rb    = (lane & 15) * 64 + rslot * 16;
    const int aoff  = wm * 8192 + rb;
    const int boff  = 16384 + wn * 4096 + rb;

#define VMWAIT(N) asm volatile("s_waitcnt vmcnt(" #N ")" ::: "memory")

#define STAGE_A(SBUF) do {                                                       \
    __builtin_amdgcn_global_load_lds((const GAS void*)(ga0),                     \
        (LAS void*)(lds + (SBUF) * 32768 + ldsw),          16, 0, 0);            \
    __builtin_amdgcn_global_load_lds((const GAS void*)(ga1),                     \
        (LAS void*)(lds + (SBUF) * 32768 + 8192  + ldsw),  16, 0, 0);            \
  } while (0)

#define STAGE_B(SBUF) do {                                                       \
    __builtin_amdgcn_global_load_lds((const GAS void*)(gb0),                     \
        (LAS void*)(lds + (SBUF) * 32768 + 16384 + ldsw),  16, 0, 0);            \
    __builtin_amdgcn_global_load_lds((const GAS void*)(gb1),                     \
        (LAS void*)(lds + (SBUF) * 32768 + 24576 + ldsw),  16, 0, 0);            \
    ga0 += BK; ga1 += BK; gb0 += BK; gb1 += BK;                                  \
  } while (0)

#define TILE_GEN(BUF, SA, SB, EW) do {                                           \
    bf16x8 bf_[4], af_[4];                                                       \
    _Pragma("unroll")                                                            \
    for (int nf_ = 0; nf_ < 4; ++nf_)                                            \
        bf_[nf_] = *reinterpret_cast<const bf16x8*>(                             \
            lds + (BUF) * 32768 + boff + nf_ * 1024);                            \
    _Pragma("unroll")                                                            \
    for (int mf_ = 0; mf_ < 4; ++mf_)                                            \
        af_[mf_] = *reinterpret_cast<const bf16x8*>(                             \
            lds + (BUF) * 32768 + aoff + mf_ * 1024);                            \
    SA;                                                                          \
    __builtin_amdgcn_s_barrier();                                                \
    asm volatile("s_waitcnt lgkmcnt(0)" ::: "memory");                           \
    __builtin_amdgcn_sched_barrier(0);                                           \
    __builtin_amdgcn_s_setprio(1);                                               \
    _Pragma("unroll")                                                            \
    for (int mf_ = 0; mf_ < 4; ++mf_)                                            \
        _Pragma("unroll")                                                        \
        for (int nf_ = 0; nf_ < 4; ++nf_)                                        \
            acc[mf_][nf_] = __builtin_amdgcn_mfma_f32_16x16x32_bf16(             \
                af_[mf_], bf_[nf_], acc[mf_][nf_], 0, 0, 0);                     \
    __builtin_amdgcn_s_setprio(0);                                               \
    __builtin_amdgcn_s_barrier();                                                \
    _Pragma("unroll")                                                            \
    for (int mf_ = 0; mf_ < 4; ++mf_)                                            \
        af_[mf_] = *reinterpret_cast<const bf16x8*>(                             \
            lds + (BUF) * 32768 + aoff + 4096 + mf_ * 1024);                     \
    SB;                                                                          \
    __builtin_amdgcn_s_barrier();                                                \
    asm volatile("s_waitcnt lgkmcnt(0)" ::: "memory");                           \
    __builtin_amdgcn_sched_barrier(0);                                           \
    __builtin_amdgcn_s_setprio(1);                                               \
    _Pragma("unroll")                                                            \
    for (int mf_ = 0; mf_ < 4; ++mf_)                                            \
        _Pragma("unroll")                                                        \
        for (int nf_ = 0; nf_ < 4; ++nf_)                                        \
            acc[4 + mf_][nf_] = __builtin_amdgcn_mfma_f32_16x16x32_bf16(         \
                af_[mf_], bf_[nf_], acc[4 + mf_][nf_], 0, 0, 0);                 \
    __builtin_amdgcn_s_setprio(0);                                               \
    EW;                                                                          \
    __builtin_amdgcn_s_barrier();                                                \
  } while (0)

#define TILE(BUF, SBUF) TILE_GEN(BUF, STAGE_A(SBUF), STAGE_B(SBUF), VMWAIT(4))
#define TAIL0(BUF)      TILE_GEN(BUF, (void)0, (void)0, VMWAIT(0))
#define TAIL1(BUF)      TILE_GEN(BUF, (void)0, (void)0, (void)0)

    STAGE_A(0); STAGE_B(0);
    STAGE_A(1); STAGE_B(1);
    VMWAIT(4);
    __builtin_amdgcn_s_barrier();

    for (int g = 0; g < 7; ++g) {
        TILE(0, 2);
        TILE(1, 3);
        TILE(2, 0);
        TILE(3, 1);
    }
    TILE(0, 2);
    TILE(1, 3);
    TAIL0(2);
    TAIL1(3);

#undef TILE
#undef TAIL0
#undef TAIL1
#undef TILE_GEN
#undef STAGE_A
#undef STAGE_B
#undef VMWAIT

    // ---- Epilogue part 1: gating transform -> LDS ----
    // B-row r = wn*64 + nf*16 + (lane&15); r<128 -> gate col j0+r, r>=128 -> hidden col j0+(r-128)
    ushort* a_lds = smem;                      // [256][132] bf16
    ushort* g_lds = smem + 33792;              // [256][132] bf16
    float*  sumA  = (float*)(smem + 67584);    // [4][128]
    float*  sumV  = sumA + 512;

    {
        const bool isG = (wn < 2);
        ushort* tgt = isG ? a_lds : g_lds;
        const int jl = (wn & 1) * 64;
        float bn[4];
#pragma unroll
        for (int nf = 0; nf < 4; ++nf)
            bn[nf] = bias[(isG ? 0 : 1024) + j0 + jl + nf * 16 + (lane & 15)];
#pragma unroll
        for (int mf = 0; mf < 8; ++mf) {
#pragma unroll
            for (int i = 0; i < 4; ++i) {
                const int m = wm * 128 + mf * 16 + (lane >> 4) * 4 + i;  // 0..255 local s
#pragma unroll
                for (int nf = 0; nf < 4; ++nf) {
                    float val = acc[mf][nf][i] + bn[nf];
                    float r;
                    if (isG) r = 1.f / (1.f + __expf(val));                 // sigmoid(-gate)
                    else     r = (val >= 0.f) ? val + 0.5f : 1.f / (1.f + __expf(-val)); // g(hidden)
                    tgt[m * 132 + jl + nf * 16 + (lane & 15)] = f2bf(r);
                }
            }
        }
    }
    __syncthreads();

    // ---- Epilogue part 2: block-local prefix scan (f32), store prefixes + summary ----
    {
        const int j  = tid & 127;     // local j
        const int sg = tid >> 7;      // segment 0..3 (64 steps each)
        float A1 = 1.f, V1 = 0.f;
#pragma unroll 4
        for (int t = 0; t < 64; ++t) {
            const int s = sg * 64 + t;
            float a = bf2f(a_lds[s * 132 + j]);
            float g = bf2f(g_lds[s * 132 + j]);
            V1 = a * V1 + (1.f - a) * g;
            A1 *= a;
        }
        sumA[sg * 128 + j] = A1;
        sumV[sg * 128 + j] = V1;
        __syncthreads();
        float Ar = 1.f, Vr = 0.f;
        for (int k = 0; k < sg; ++k) {
            float Ak = sumA[k * 128 + j], Vk = sumV[k * 128 + j];
            Vr = Ak * Vr + Vk;
            Ar *= Ak;
        }
        ushort* ApG = Apref + (size_t)(m0 + sg * 64) * kH + j0 + j;
        ushort* VpG = Vpref + (size_t)(m0 + sg * 64) * kH + j0 + j;
#pragma unroll 4
        for (int t = 0; t < 64; ++t) {
            const int s = sg * 64 + t;
            float a = bf2f(a_lds[s * 132 + j]);
            float g = bf2f(g_lds[s * 132 + j]);
            Vr = a * Vr + (1.f - a) * g;
            Ar *= a;
            *ApG = f2bf(Ar);
            *VpG = f2bf(Vr);
            ApG += kH; VpG += kH;
        }
        if (sg == 3) {
            const int b = tm >> 3, c = tm & 7;      // chunk = 256 steps = this block
            cA[((b * 8 + c) << 10) + j0 + j] = Ar;  // f32 summary
            cV[((b * 8 + c) << 10) + j0 + j] = Vr;
        }
    }
}

// ---------------- mid-scan over 8 chunks/b; emits h_chunkstart + h_final ----------------
__global__ void scan_chunks_kernel(const float* __restrict__ cA, const float* __restrict__ cV,
                                   const float* __restrict__ h0, float* __restrict__ hstart,
                                   float* __restrict__ hfin)
{
    int idx = blockIdx.x * 256 + threadIdx.x;     // 8192 threads: (b, j)
    int j = idx & 1023, b = idx >> 10;
    float h = h0[(b << 10) + j];
    for (int c = 0; c < 8; ++c) {
        int o = ((b * 8 + c) << 10) + j;
        hstart[o] = h;
        h = cA[o] * h + cV[o];
    }
    hfin[(b << 10) + j] = h;
}

// ---------------- apply: elementwise out = A_pref*h_cs + V_pref + residual ----------------
template<bool WRITE_F32>
__global__ void apply_kernel(const ushort* __restrict__ Ap, const ushort* __restrict__ Vp,
                             const float* __restrict__ hst, const ushort* __restrict__ res,
                             void* __restrict__ outp)
{
    size_t i = ((size_t)blockIdx.x * 256 + threadIdx.x) * 4;
    int m = (int)(i >> 10);          // row
    int j = (int)(i & 1023);
    int b = m >> 11, s = m & 2047, c = s >> 8;
    f32x4 hcs = *reinterpret_cast<const f32x4*>(hst + (((b * 8 + c) << 10) + j));
    ushort4 Au = *reinterpret_cast<const ushort4*>(Ap + i);
    ushort4 Vu = *reinterpret_cast<const ushort4*>(Vp + i);
    ushort4 Ru = *reinterpret_cast<const ushort4*>(res + i);
    f32x4 o;
    o.x = bf2f(Au.x) * hcs.x + bf2f(Vu.x) + bf2f(Ru.x);
    o.y = bf2f(Au.y) * hcs.y + bf2f(Vu.y) + bf2f(Ru.y);
    o.z = bf2f(Au.z) * hcs.z + bf2f(Vu.z) + bf2f(Ru.z);
    o.w = bf2f(Au.w) * hcs.w + bf2f(Vu.w) + bf2f(Ru.w);
    if (WRITE_F32) {
        *reinterpret_cast<f32x4*>((float*)outp + i) = o;
    } else {
        ushort4 ob;
        ob.x = f2bf(o.x); ob.y = f2bf(o.y); ob.z = f2bf(o.z); ob.w = f2bf(o.w);
        *reinterpret_cast<ushort4*>((ushort*)outp + i) = ob;
    }
}

extern "C" void kernel_launch(void* const* d_in, const int* in_sizes, int n_in,
                              void* d_out, int out_size, void* d_ws, size_t ws_size,
                              hipStream_t stream)
{
    const float* x  = (const float*)d_in[0];
    const float* h  = (const float*)d_in[1];   // (2, 8, 1, 1024)
    const float* w0 = (const float*)d_in[2];
    const float* b0 = (const float*)d_in[3];
    const float* w1 = (const float*)d_in[4];
    const float* b1 = (const float*)d_in[5];
    float* out = (float*)d_out;
    char* ws = (char*)d_ws;

    if (ws_size < kWsNeed) return;

    ushort* xb   = (ushort*)(ws + kOffXb);   // aliases inpb (apply-L0 overwrites in place)
    ushort* inpb = (ushort*)(ws + kOffXb);
    ushort* w0b  = (ushort*)(ws + kOffW0);
    ushort* w1b  = (ushort*)(ws + kOffW1);
    ushort* Ap   = (ushort*)(ws + kOffA);
    ushort* Vp   = (ushort*)(ws + kOffG);
    float*  cA   = (float*)(ws + kOffCA);
    float*  cV   = (float*)(ws + kOffCV);
    float*  hst  = (float*)(ws + kOffHst);

    float* out_h = out + (size_t)kM * kH;    // h_final region in d_out

    cvt_bf16_kernel<<<(kM * kK / 4 + 255) / 256, 256, 0, stream>>>(x, xb, kM * kK / 4);
    cvt_bf16_kernel<<<(kN2 * kK / 4 + 255) / 256, 256, 0, stream>>>(w0, w0b, kN2 * kK / 4);
    cvt_bf16_kernel<<<(kN2 * kK / 4 + 255) / 256, 256, 0, stream>>>(w1, w1b, kN2 * kK / 4);

    const int gemm_grid  = (kM / BM) * (kN2 / BN);   // 512
    const int apply_grid = kM * kH / 4 / 256;        // 16384

    // ---- layer 0 ----
    gemm_scan_kernel<<<gemm_grid, 512, 0, stream>>>(xb, w0b, b0, Ap, Vp, cA, cV);
    scan_chunks_kernel<<<32, 256, 0, stream>>>(cA, cV, h, hst, out_h);
    apply_kernel<false><<<apply_grid, 256, 0, stream>>>(Ap, Vp, hst, xb, inpb);

    // ---- layer 1 ----
    gemm_scan_kernel<<<gemm_grid, 512, 0, stream>>>(inpb, w1b, b1, Ap, Vp, cA, cV);
    scan_chunks_kernel<<<32, 256, 0, stream>>>(cA, cV, h + (size_t)kB * kH, hst, out_h + (size_t)kB * kH);
    apply_kernel<true><<<apply_grid, 256, 0, stream>>>(Ap, Vp, hst, inpb, out);
}